// Round 5
// baseline (340.796 us; speedup 1.0000x reference)
//
#include <hip/hip_runtime.h>

#define D 4096
#define RANK 8

typedef float f4 __attribute__((ext_vector_type(4)));

// ===========================================================================
// Three-kernel barrier-free formulation.
//   H = I - Vn T Vn^T  (compact WY, Vn = column-normalized hra_u)
//   y_row = x_row - sum_k C[row][k] * B[k][:],  where
//   C[row][k] = sum_d x[row][d] Vn[d][k],  B[k][d] = sum_j Vn[d][j] T[j][k]
// K0: setup (1 block)   -> Vn[D][8], B[8][D] in workspace
// K1: dots  (streaming) -> C[rows][8]; one wave per row-pair, wave-local
//                          butterfly only, NO block barriers
// K2: apply (streaming) -> y; no reductions at all, nontemporal y stores
// Rationale (r0-r4 post-mortems): fused 16-wave block + per-pair barrier is
// duty-cycle-limited at ~2 TB/s, 44% occupancy; occupancy cannot be raised
// (64 VGPR -> 1 block/CU; forcing 32 VGPR -> 5.6x spill traffic). r3 showed
// this access pattern sustains 3.87 TB/s once waves are resident.
// ===========================================================================

// ---------------------------------------------------------------------------
// K0: compute Vn and B (one 1024-thread block; prologue identical to the
// verified fused kernel's setup phase).
// ---------------------------------------------------------------------------
__global__ __launch_bounds__(1024) void hra_setup(
    const float* __restrict__ u_raw, float* __restrict__ vn_out,
    float* __restrict__ B_out) {
  __shared__ float s_g[16][36];
  __shared__ float s_G[36];
  __shared__ float s_Gn[64];
  __shared__ float s_T[64];
  __shared__ float s_invn[8];

  const int t = threadIdx.x;
  const int lane = t & 63;
  const int wid = t >> 6;

  float v[4][8];
#pragma unroll
  for (int q = 0; q < 4; ++q) {
    const int d = 4 * t + q;
    const f4* p = (const f4*)(u_raw + (size_t)d * RANK);
    f4 a0 = p[0];
    f4 a1 = p[1];
    v[q][0] = a0.x; v[q][1] = a0.y; v[q][2] = a0.z; v[q][3] = a0.w;
    v[q][4] = a1.x; v[q][5] = a1.y; v[q][6] = a1.z; v[q][7] = a1.w;
  }

  {  // Gram partials (packed upper triangle)
    float g[36];
#pragma unroll
    for (int k = 0; k < 36; ++k) g[k] = 0.f;
#pragma unroll
    for (int q = 0; q < 4; ++q) {
      int idx = 0;
#pragma unroll
      for (int i = 0; i < 8; ++i)
#pragma unroll
        for (int j = i; j < 8; ++j)
          g[idx++] += v[q][i] * v[q][j];
    }
#pragma unroll
    for (int off = 32; off >= 1; off >>= 1) {
#pragma unroll
      for (int k = 0; k < 36; ++k)
        g[k] += __shfl_xor(g[k], off, 64);
    }
    if (lane == 0) {
#pragma unroll
      for (int k = 0; k < 36; ++k) s_g[wid][k] = g[k];
    }
  }
  __syncthreads();

  if (t < 36) {
    float s = 0.f;
#pragma unroll
    for (int w2 = 0; w2 < 16; ++w2) s += s_g[w2][t];
    s_G[t] = s;
  }
  __syncthreads();

  if (t < 8) {
    const int dix[8] = {0, 8, 15, 21, 26, 30, 33, 35};
    s_invn[t] = rsqrtf(s_G[dix[t]]);
  }
  __syncthreads();

  if (t < 64) {
    const int i = t >> 3, j = t & 7;
    const int ii = i < j ? i : j;
    const int jj = i < j ? j : i;
    const int idx = ii * 8 - (ii * (ii - 1)) / 2 + (jj - ii);
    s_Gn[t] = s_G[idx] * s_invn[i] * s_invn[j];
  }
  __syncthreads();

  if (t < 8) {  // column-parallel WY recurrence
    const int j = t;
    for (int k = 0; k < j; ++k) s_T[k * 8 + j] = 0.f;
    s_T[j * 8 + j] = 2.f;
    for (int k = j + 1; k < 8; ++k) {
      float s = 0.f;
      for (int l = j; l < k; ++l) s += s_Gn[k * 8 + l] * s_T[l * 8 + j];
      s_T[k * 8 + j] = -2.f * s;
    }
  }
  __syncthreads();

  // normalize V
  {
    float invn[8];
#pragma unroll
    for (int i = 0; i < 8; ++i) invn[i] = s_invn[i];
#pragma unroll
    for (int q = 0; q < 4; ++q)
#pragma unroll
      for (int i = 0; i < 8; ++i) v[q][i] *= invn[i];
  }

  // write Vn[d][8] (row-major, d-major)
#pragma unroll
  for (int q = 0; q < 4; ++q) {
    f4 lo = {v[q][0], v[q][1], v[q][2], v[q][3]};
    f4 hi = {v[q][4], v[q][5], v[q][6], v[q][7]};
    f4* p = (f4*)(vn_out + (size_t)(4 * t + q) * RANK);
    p[0] = lo;
    p[1] = hi;
  }

  // B[k][d] = sum_j Vn[d][j] * T[j][k]; thread owns d = 4t..4t+3
#pragma unroll
  for (int k = 0; k < 8; ++k) {
    float Tk[8];
#pragma unroll
    for (int j = 0; j < 8; ++j) Tk[j] = s_T[j * 8 + k];  // uniform -> broadcast
    f4 b;
    float bq[4];
#pragma unroll
    for (int q = 0; q < 4; ++q) {
      float s = 0.f;
#pragma unroll
      for (int j = 0; j < 8; ++j) s += v[q][j] * Tk[j];
      bq[q] = s;
    }
    b.x = bq[0]; b.y = bq[1]; b.z = bq[2]; b.w = bq[3];
    *(f4*)(B_out + (size_t)k * D + 4 * t) = b;
  }
}

// ---------------------------------------------------------------------------
// K1: C = X * Vn. One wave per row-pair; Vn streamed from L2 (128 KB hot),
// amortized over 2 rows. Wave-level butterfly; no block barriers.
// ---------------------------------------------------------------------------
#define K1_BLOCK 256
__global__ __launch_bounds__(K1_BLOCK) void hra_dots(
    const float* __restrict__ x_in, const float* __restrict__ vn,
    float* __restrict__ C, int rows) {
  const int lane = threadIdx.x & 63;
  const int wv = blockIdx.x * (K1_BLOCK / 64) + (threadIdx.x >> 6);
  const int r0 = wv * 2;
  if (r0 >= rows) return;

  const float* x0 = x_in + (size_t)r0 * D;
  const float* x1 = x0 + D;

  float acc0[8], acc1[8];
#pragma unroll
  for (int i = 0; i < 8; ++i) { acc0[i] = 0.f; acc1[i] = 0.f; }

#pragma unroll 2
  for (int k = 0; k < 16; ++k) {
    const int d = k * 256 + lane * 4;
    f4 a = *(const f4*)(x0 + d);
    f4 b = *(const f4*)(x1 + d);
    const f4* vp = (const f4*)(vn + (size_t)d * RANK);
    const float xa[4] = {a.x, a.y, a.z, a.w};
    const float xb[4] = {b.x, b.y, b.z, b.w};
#pragma unroll
    for (int q = 0; q < 4; ++q) {
      f4 vlo = vp[2 * q];
      f4 vhi = vp[2 * q + 1];
      acc0[0] += xa[q] * vlo.x; acc0[1] += xa[q] * vlo.y;
      acc0[2] += xa[q] * vlo.z; acc0[3] += xa[q] * vlo.w;
      acc0[4] += xa[q] * vhi.x; acc0[5] += xa[q] * vhi.y;
      acc0[6] += xa[q] * vhi.z; acc0[7] += xa[q] * vhi.w;
      acc1[0] += xb[q] * vlo.x; acc1[1] += xb[q] * vlo.y;
      acc1[2] += xb[q] * vlo.z; acc1[3] += xb[q] * vlo.w;
      acc1[4] += xb[q] * vhi.x; acc1[5] += xb[q] * vhi.y;
      acc1[6] += xb[q] * vhi.z; acc1[7] += xb[q] * vhi.w;
    }
  }

#pragma unroll
  for (int off = 32; off >= 1; off >>= 1) {
#pragma unroll
    for (int i = 0; i < 8; ++i) {
      acc0[i] += __shfl_xor(acc0[i], off, 64);
      acc1[i] += __shfl_xor(acc1[i], off, 64);
    }
  }

  if (lane == 0) {
    f4 c0 = {acc0[0], acc0[1], acc0[2], acc0[3]};
    f4 c1 = {acc0[4], acc0[5], acc0[6], acc0[7]};
    f4 c2 = {acc1[0], acc1[1], acc1[2], acc1[3]};
    f4 c3 = {acc1[4], acc1[5], acc1[6], acc1[7]};
    f4* cp = (f4*)(C + (size_t)r0 * RANK);
    cp[0] = c0; cp[1] = c1; cp[2] = c2; cp[3] = c3;
  }
}

// ---------------------------------------------------------------------------
// K2: y = x - C * B. Pure streaming; B chunk (8 f4 = 32 regs) reused over
// 32 rows; no reductions, no barriers. Nontemporal y stores keep X resident
// in L3 for this kernel's own reads.
// ---------------------------------------------------------------------------
#define K2_BLOCK 256
#define K2_ROWS 32
__global__ __launch_bounds__(K2_BLOCK) void hra_apply(
    const float* __restrict__ x_in, const float* __restrict__ C,
    const float* __restrict__ B, float* __restrict__ y, int rows) {
  const int t = threadIdx.x;
  const int dq = blockIdx.x & 3;   // which quarter of D
  const int rt = blockIdx.x >> 2;  // row tile
  const int d = dq * (K2_BLOCK * 4) + 4 * t;
  const int r0 = rt * K2_ROWS;

  f4 Bk[8];
#pragma unroll
  for (int k = 0; k < 8; ++k) Bk[k] = *(const f4*)(B + (size_t)k * D + d);

#pragma unroll 4
  for (int r = 0; r < K2_ROWS; ++r) {
    const size_t off = (size_t)(r0 + r) * D + d;
    f4 x = *(const f4*)(x_in + off);
    const f4* cp = (const f4*)(C + (size_t)(r0 + r) * RANK);
    f4 clo = cp[0];
    f4 chi = cp[1];
    const float c[8] = {clo.x, clo.y, clo.z, clo.w,
                        chi.x, chi.y, chi.z, chi.w};
    f4 s = {0.f, 0.f, 0.f, 0.f};
#pragma unroll
    for (int k = 0; k < 8; ++k) s += c[k] * Bk[k];
    f4 out = x - s;
    __builtin_nontemporal_store(out, (f4*)(y + off));
  }
}

extern "C" void kernel_launch(void* const* d_in, const int* in_sizes, int n_in,
                              void* d_out, int out_size, void* d_ws, size_t ws_size,
                              hipStream_t stream) {
  const float* x_in = (const float*)d_in[0];
  const float* u = (const float*)d_in[1];
  float* y = (float*)d_out;
  (void)n_in; (void)out_size; (void)ws_size;

  const int rows = in_sizes[0] / D;  // 8192 (in_sizes in elements)

  float* vn = (float*)d_ws;          // D*8 floats   = 128 KB
  float* B = vn + (size_t)D * RANK;  // 8*D floats   = 128 KB
  float* C = B + (size_t)RANK * D;   // rows*8 floats = 256 KB

  hipLaunchKernelGGL(hra_setup, dim3(1), dim3(1024), 0, stream, u, vn, B);

  // one wave per row-pair: rows/2 waves, 4 waves/block
  const int grid1 = (rows / 2) / (K1_BLOCK / 64);  // 1024
  hipLaunchKernelGGL(hra_dots, dim3(grid1), dim3(K1_BLOCK), 0, stream,
                     x_in, vn, C, rows);

  const int grid2 = (D / (K2_BLOCK * 4)) * (rows / K2_ROWS);  // 4*256 = 1024
  hipLaunchKernelGGL(hra_apply, dim3(grid2), dim3(K2_BLOCK), 0, stream,
                     x_in, C, B, y, rows);
}

// Round 6
// 294.625 us; speedup vs baseline: 1.1567x; 1.1567x over previous
//
#include <hip/hip_runtime.h>

#define D 4096
#define RANK 8

typedef float f4 __attribute__((ext_vector_type(4)));

// ===========================================================================
// Three-kernel barrier-free formulation (round 6: coalescing fix).
//   H = I - Vn T Vn^T  (compact WY, Vn = column-normalized hra_u)
//   C[r][k] = sum_d X[r][d] * VnT[k][d]
//   y[r][d] = x[r][d] - sum_k C[r][k] * B[k][d],  B[k][d] = sum_j Vn[d][j]T[j][k]
// K0: setup (1 block) -> VnT[8][D] (k-major!), B[8][D] in workspace.
// K1: dots            -> C[rows][8]; one wave per row-pair. Round-5 version
//     loaded Vn d-major: lane stride 128 B = fully uncoalesced, 64 cache
//     lines per load instruction -> 100 us @ 670 GB/s. VnT rows are
//     16 B/lane coalesced.
// K2: apply           -> y; C staged in LDS once per block, unroll-8 row
//     loop, nontemporal y stores (keep X in L3 for K2's own reads).
// ===========================================================================

// ---------------------------------------------------------------------------
// K0: compute VnT and B (one 1024-thread block; prologue identical to the
// verified fused kernel's setup phase).
// ---------------------------------------------------------------------------
__global__ __launch_bounds__(1024) void hra_setup(
    const float* __restrict__ u_raw, float* __restrict__ vnT_out,
    float* __restrict__ B_out) {
  __shared__ float s_g[16][36];
  __shared__ float s_G[36];
  __shared__ float s_Gn[64];
  __shared__ float s_T[64];
  __shared__ float s_invn[8];

  const int t = threadIdx.x;
  const int lane = t & 63;
  const int wid = t >> 6;

  float v[4][8];
#pragma unroll
  for (int q = 0; q < 4; ++q) {
    const int d = 4 * t + q;
    const f4* p = (const f4*)(u_raw + (size_t)d * RANK);
    f4 a0 = p[0];
    f4 a1 = p[1];
    v[q][0] = a0.x; v[q][1] = a0.y; v[q][2] = a0.z; v[q][3] = a0.w;
    v[q][4] = a1.x; v[q][5] = a1.y; v[q][6] = a1.z; v[q][7] = a1.w;
  }

  {  // Gram partials (packed upper triangle)
    float g[36];
#pragma unroll
    for (int k = 0; k < 36; ++k) g[k] = 0.f;
#pragma unroll
    for (int q = 0; q < 4; ++q) {
      int idx = 0;
#pragma unroll
      for (int i = 0; i < 8; ++i)
#pragma unroll
        for (int j = i; j < 8; ++j)
          g[idx++] += v[q][i] * v[q][j];
    }
#pragma unroll
    for (int off = 32; off >= 1; off >>= 1) {
#pragma unroll
      for (int k = 0; k < 36; ++k)
        g[k] += __shfl_xor(g[k], off, 64);
    }
    if (lane == 0) {
#pragma unroll
      for (int k = 0; k < 36; ++k) s_g[wid][k] = g[k];
    }
  }
  __syncthreads();

  if (t < 36) {
    float s = 0.f;
#pragma unroll
    for (int w2 = 0; w2 < 16; ++w2) s += s_g[w2][t];
    s_G[t] = s;
  }
  __syncthreads();

  if (t < 8) {
    const int dix[8] = {0, 8, 15, 21, 26, 30, 33, 35};
    s_invn[t] = rsqrtf(s_G[dix[t]]);
  }
  __syncthreads();

  if (t < 64) {
    const int i = t >> 3, j = t & 7;
    const int ii = i < j ? i : j;
    const int jj = i < j ? j : i;
    const int idx = ii * 8 - (ii * (ii - 1)) / 2 + (jj - ii);
    s_Gn[t] = s_G[idx] * s_invn[i] * s_invn[j];
  }
  __syncthreads();

  if (t < 8) {  // column-parallel WY recurrence
    const int j = t;
    for (int k = 0; k < j; ++k) s_T[k * 8 + j] = 0.f;
    s_T[j * 8 + j] = 2.f;
    for (int k = j + 1; k < 8; ++k) {
      float s = 0.f;
      for (int l = j; l < k; ++l) s += s_Gn[k * 8 + l] * s_T[l * 8 + j];
      s_T[k * 8 + j] = -2.f * s;
    }
  }
  __syncthreads();

  // normalize V
  {
    float invn[8];
#pragma unroll
    for (int i = 0; i < 8; ++i) invn[i] = s_invn[i];
#pragma unroll
    for (int q = 0; q < 4; ++q)
#pragma unroll
      for (int i = 0; i < 8; ++i) v[q][i] *= invn[i];
  }

  // VnT[k][d] (k-major): thread owns d = 4t..4t+3 -> coalesced f4 stores
#pragma unroll
  for (int k = 0; k < 8; ++k) {
    f4 b = {v[0][k], v[1][k], v[2][k], v[3][k]};
    *(f4*)(vnT_out + (size_t)k * D + 4 * t) = b;
  }

  // B[k][d] = sum_j Vn[d][j] * T[j][k]
#pragma unroll
  for (int k = 0; k < 8; ++k) {
    float Tk[8];
#pragma unroll
    for (int j = 0; j < 8; ++j) Tk[j] = s_T[j * 8 + k];  // uniform -> broadcast
    float bq[4];
#pragma unroll
    for (int q = 0; q < 4; ++q) {
      float s = 0.f;
#pragma unroll
      for (int j = 0; j < 8; ++j) s += v[q][j] * Tk[j];
      bq[q] = s;
    }
    f4 b = {bq[0], bq[1], bq[2], bq[3]};
    *(f4*)(B_out + (size_t)k * D + 4 * t) = b;
  }
}

// ---------------------------------------------------------------------------
// K1: C = X * Vn via VnT. One wave per row-pair. Per iteration: 2 coalesced
// X loads + 8 coalesced VnT row loads (shared by both rows), 64 FMAs.
// Wave-level butterfly only; no block barriers.
// ---------------------------------------------------------------------------
#define K1_BLOCK 256
__global__ __launch_bounds__(K1_BLOCK) void hra_dots(
    const float* __restrict__ x_in, const float* __restrict__ vnT,
    float* __restrict__ C, int rows) {
  const int lane = threadIdx.x & 63;
  const int wv = blockIdx.x * (K1_BLOCK / 64) + (threadIdx.x >> 6);
  const int r0 = wv * 2;
  if (r0 >= rows) return;

  const float* x0 = x_in + (size_t)r0 * D;
  const float* x1 = x0 + D;

  float acc0[8], acc1[8];
#pragma unroll
  for (int i = 0; i < 8; ++i) { acc0[i] = 0.f; acc1[i] = 0.f; }

#pragma unroll 2
  for (int it = 0; it < 16; ++it) {
    const int d = it * 256 + lane * 4;
    f4 a = *(const f4*)(x0 + d);
    f4 b = *(const f4*)(x1 + d);
    f4 vk[8];
#pragma unroll
    for (int k = 0; k < 8; ++k)
      vk[k] = *(const f4*)(vnT + (size_t)k * D + d);
#pragma unroll
    for (int k = 0; k < 8; ++k) {
      acc0[k] += a.x * vk[k].x + a.y * vk[k].y + a.z * vk[k].z + a.w * vk[k].w;
      acc1[k] += b.x * vk[k].x + b.y * vk[k].y + b.z * vk[k].z + b.w * vk[k].w;
    }
  }

#pragma unroll
  for (int off = 32; off >= 1; off >>= 1) {
#pragma unroll
    for (int i = 0; i < 8; ++i) {
      acc0[i] += __shfl_xor(acc0[i], off, 64);
      acc1[i] += __shfl_xor(acc1[i], off, 64);
    }
  }

  if (lane == 0) {
    f4 c0 = {acc0[0], acc0[1], acc0[2], acc0[3]};
    f4 c1 = {acc0[4], acc0[5], acc0[6], acc0[7]};
    f4 c2 = {acc1[0], acc1[1], acc1[2], acc1[3]};
    f4 c3 = {acc1[4], acc1[5], acc1[6], acc1[7]};
    f4* cp = (f4*)(C + (size_t)r0 * RANK);
    cp[0] = c0; cp[1] = c1; cp[2] = c2; cp[3] = c3;
  }
}

// ---------------------------------------------------------------------------
// K2: y = x - C * B. C for the block's 32 rows staged in LDS once (single
// barrier per block); unroll-8 row loop keeps >=8 X loads in flight.
// Nontemporal y stores avoid evicting X from L3.
// ---------------------------------------------------------------------------
#define K2_BLOCK 256
#define K2_ROWS 32
__global__ __launch_bounds__(K2_BLOCK) void hra_apply(
    const float* __restrict__ x_in, const float* __restrict__ C,
    const float* __restrict__ B, float* __restrict__ y, int rows) {
  __shared__ float sc[K2_ROWS][RANK];
  const int t = threadIdx.x;
  const int dq = blockIdx.x & 3;   // which quarter of D
  const int rt = blockIdx.x >> 2;  // row tile
  const int d = dq * (K2_BLOCK * 4) + 4 * t;
  const int r0 = rt * K2_ROWS;

  if (t < K2_ROWS * RANK) {
    sc[t >> 3][t & 7] = C[(size_t)(r0 + (t >> 3)) * RANK + (t & 7)];
  }

  f4 Bk[8];
#pragma unroll
  for (int k = 0; k < 8; ++k) Bk[k] = *(const f4*)(B + (size_t)k * D + d);

  __syncthreads();  // one barrier per block (sc ready)

#pragma unroll 8
  for (int r = 0; r < K2_ROWS; ++r) {
    const size_t off = (size_t)(r0 + r) * D + d;
    f4 x = *(const f4*)(x_in + off);
    f4 s = {0.f, 0.f, 0.f, 0.f};
#pragma unroll
    for (int k = 0; k < 8; ++k) s += sc[r][k] * Bk[k];
    f4 out = x - s;
    __builtin_nontemporal_store(out, (f4*)(y + off));
  }
}

extern "C" void kernel_launch(void* const* d_in, const int* in_sizes, int n_in,
                              void* d_out, int out_size, void* d_ws, size_t ws_size,
                              hipStream_t stream) {
  const float* x_in = (const float*)d_in[0];
  const float* u = (const float*)d_in[1];
  float* y = (float*)d_out;
  (void)n_in; (void)out_size; (void)ws_size;

  const int rows = in_sizes[0] / D;  // 8192

  float* vnT = (float*)d_ws;           // 8*D floats   = 128 KB
  float* B = vnT + (size_t)RANK * D;   // 8*D floats   = 128 KB
  float* C = B + (size_t)RANK * D;     // rows*8 floats = 256 KB

  hipLaunchKernelGGL(hra_setup, dim3(1), dim3(1024), 0, stream, u, vnT, B);

  // one wave per row-pair: rows/2 waves, 4 waves/block
  const int grid1 = (rows / 2) / (K1_BLOCK / 64);  // 1024
  hipLaunchKernelGGL(hra_dots, dim3(grid1), dim3(K1_BLOCK), 0, stream,
                     x_in, vnT, C, rows);

  const int grid2 = (D / (K2_BLOCK * 4)) * (rows / K2_ROWS);  // 4*256 = 1024
  hipLaunchKernelGGL(hra_apply, dim3(grid2), dim3(K2_BLOCK), 0, stream,
                     x_in, C, B, y, rows);
}